// Round 10
// baseline (106.041 us; speedup 1.0000x reference)
//
#include <hip/hip_runtime.h>

#define NC 640
#define NQ 2048
#define NW 64

typedef unsigned short u16;
typedef unsigned int u32;
typedef __attribute__((ext_vector_type(8))) short short8;
typedef __attribute__((ext_vector_type(4))) float f32x4;
typedef __attribute__((ext_vector_type(2))) float f32x2;
typedef __attribute__((address_space(3))) void* lds_ptr_t;
typedef const __attribute__((address_space(1))) void* glb_ptr_t;

// KC = log2(e)/EPS, EPS = 0.05
constexpr float KC = 28.853900817779268f;

static __device__ __forceinline__ float hrcp(float x) { return __builtin_amdgcn_rcpf(x); }
static __device__ __forceinline__ u16 f2bf(float f) {
  u32 u = __float_as_uint(f);
  u += 0x7FFF + ((u >> 16) & 1);
  return (u16)(u >> 16);
}
static __device__ __forceinline__ float bf2f(u16 h) {
  return __uint_as_float(((u32)h) << 16);
}

// ---------------------------------------------------------------------------
// Sinkhorn core with f32x2-packed FMA chains (v_pk_fma_f32).
// ---------------------------------------------------------------------------
static __device__ __forceinline__ float sinkhorn_core(const float* sm, const float* dot) {
  float a[5];
  float suma = 0.f;
#pragma unroll
  for (int p = 0; p < 5; p++) {
    a[p] = fmaxf(dot[p], 0.f) + 0.00101f;
    suma += a[p];
  }
  float rs = 5.0f / suma;
#pragma unroll
  for (int p = 0; p < 5; p++) a[p] *= rs;

  float Km[25];
#pragma unroll
  for (int i = 0; i < 25; i++) Km[i] = __builtin_amdgcn_exp2f((sm[i] - 1.0f) * KC);

  f32x2 KP01[5], KP23[5], KQ01[5], KQ23[5];
#pragma unroll
  for (int j = 0; j < 5; j++) {
    KP01[j] = (f32x2){Km[0 * 5 + j], Km[1 * 5 + j]};
    KP23[j] = (f32x2){Km[2 * 5 + j], Km[3 * 5 + j]};
  }
#pragma unroll
  for (int i = 0; i < 5; i++) {
    KQ01[i] = (f32x2){Km[i * 5 + 0], Km[i * 5 + 1]};
    KQ23[i] = (f32x2){Km[i * 5 + 2], Km[i * 5 + 3]};
  }

  float u[5], v[5];
#pragma unroll
  for (int p = 0; p < 5; p++) { u[p] = 1.f; v[p] = 1.f; }

  for (int it = 0; it < 100; ++it) {
    f32x2 kv01 = (f32x2){0.f, 0.f}, kv23 = (f32x2){0.f, 0.f};
    float kv4 = 0.f;
#pragma unroll
    for (int j = 0; j < 5; j++) {
      f32x2 vb = (f32x2){v[j], v[j]};
      kv01 = __builtin_elementwise_fma(KP01[j], vb, kv01);
      kv23 = __builtin_elementwise_fma(KP23[j], vb, kv23);
      kv4 = fmaf(Km[20 + j], v[j], kv4);
    }
    u[0] = a[0] * hrcp(kv01.x);
    u[1] = a[1] * hrcp(kv01.y);
    u[2] = a[2] * hrcp(kv23.x);
    u[3] = a[3] * hrcp(kv23.y);
    u[4] = a[4] * hrcp(kv4);
    f32x2 ku01 = (f32x2){0.f, 0.f}, ku23 = (f32x2){0.f, 0.f};
    float ku4 = 0.f;
#pragma unroll
    for (int i = 0; i < 5; i++) {
      f32x2 ub = (f32x2){u[i], u[i]};
      ku01 = __builtin_elementwise_fma(KQ01[i], ub, ku01);
      ku23 = __builtin_elementwise_fma(KQ23[i], ub, ku23);
      ku4 = fmaf(Km[i * 5 + 4], u[i], ku4);
    }
    v[0] = a[0] * hrcp(ku01.x);
    v[1] = a[1] * hrcp(ku01.y);
    v[2] = a[2] * hrcp(ku23.x);
    v[3] = a[3] * hrcp(ku23.y);
    v[4] = a[4] * hrcp(ku4);
  }

  float acc = 0.f;
#pragma unroll
  for (int i = 0; i < 5; i++)
#pragma unroll
    for (int j = 0; j < 5; j++)
      acc += u[i] * Km[i * 5 + j] * v[j] * sm[i * 5 + j];
  return acc * 2.5f;
}

// ---------------------------------------------------------------------------
// Per-thread patch means + block stats over 10 waves. bc = {mu[5], nrm[5]}.
// ---------------------------------------------------------------------------
static __device__ __forceinline__ void feat_compute(const float* v, float* f,
                                                    float* bc, float (*wred)[10],
                                                    int t) {
  {
    float lt = 0.f, rt = 0.f, mid = 0.f, lb = 0.f, rb = 0.f;
#pragma unroll
    for (int i = 0; i < 3; i++)
#pragma unroll
      for (int j = 0; j < 3; j++) {
        lt += v[i * 5 + j];
        rt += v[(i + 2) * 5 + j];
        lb += v[i * 5 + (j + 2)];
        rb += v[(i + 2) * 5 + (j + 2)];
      }
#pragma unroll
    for (int i = 1; i < 5; i++)
#pragma unroll
      for (int j = 1; j < 5; j++) mid += v[i * 5 + j];
    f[0] = lt * (1.f / 9.f);
    f[1] = rt * (1.f / 9.f);
    f[2] = mid * (1.f / 16.f);
    f[3] = lb * (1.f / 9.f);
    f[4] = rb * (1.f / 9.f);
  }
  float s[10];
#pragma unroll
  for (int p = 0; p < 5; p++) { s[p] = f[p]; s[5 + p] = f[p] * f[p]; }
#pragma unroll
  for (int off = 32; off > 0; off >>= 1)
#pragma unroll
    for (int k = 0; k < 10; k++) s[k] += __shfl_xor(s[k], off);
  const int lane = t & 63;
  const int wv = t >> 6;
  if (lane == 0) {
#pragma unroll
    for (int k = 0; k < 10; k++) wred[wv][k] = s[k];
  }
  __syncthreads();
  if (t < 5) {
    float s1 = 0.f, s2 = 0.f;
#pragma unroll
    for (int w = 0; w < 10; w++) { s1 += wred[w][t]; s2 += wred[w][5 + t]; }
    float mu = s1 * (1.0f / NC);
    float n2 = fmaxf(s2 - (float)NC * mu * mu, 0.0f);
    float nrm = fmaxf(sqrtf(n2), 1e-8f);
    bc[t] = mu;
    bc[5 + t] = nrm;
  }
  __syncthreads();
}

// ---------------------------------------------------------------------------
// Feature kernel v6 (R2/R4 skeleton, best-measured): one block = one sample,
// 640 threads; whole 64KB staged via plain float4 VGPR loads (7/thread,
// compiler-pipelined) -> LDS; one syncthreads; per-channel compute from
// lin[t*25+j] (25 coprime 32 -> free); 2-barrier block stats; barrier-free
// shfl-pair-packed u32 hi/lo stores. Blocks [0,2048): query; rest: proto.
// ---------------------------------------------------------------------------
__global__ __launch_bounds__(640) void feat_kernel(const float* __restrict__ q,
                                                   const float* __restrict__ pr,
                                                   u16* __restrict__ Ah,
                                                   u16* __restrict__ Al,
                                                   u16* __restrict__ Bh,
                                                   u16* __restrict__ Bl,
                                                   float* __restrict__ statsQ,
                                                   float* __restrict__ statsP)
{
  __shared__ float lin[16000];
  __shared__ float wred[10][10];
  __shared__ float bc[10];
  const int bid = blockIdx.x;
  const bool isQ = (bid < NQ);
  const int n = isQ ? bid : bid - NQ;
  const float* __restrict__ x = (isQ ? q : pr) + (size_t)n * 16000;
  const int t = threadIdx.x;

  // stage: 4000 float4, plain VGPR loads (compiler pipelines these deep)
  {
    const float4* src = (const float4*)x;
    float4* dst = (float4*)lin;
#pragma unroll
    for (int i = 0; i < 6; i++) dst[t + i * 640] = src[t + i * 640];
    if (t < 160) dst[t + 3840] = src[t + 3840];
  }
  __syncthreads();

  float f[5];
  feat_compute(lin + t * 25, f, bc, wred, t);

  if (t < 5) {
    if (isQ) {
      statsQ[(size_t)n * 10 + t] = bc[t];
      statsQ[(size_t)n * 10 + 5 + t] = bc[5 + t];
    } else {
      statsP[t * NW + n] = bc[t];
      statsP[(5 + t) * NW + n] = bc[5 + t];
    }
  }

  // centered-normalized split-bf16 writes: shfl pair-pack, even lanes store
  u32* __restrict__ Oh = (u32*)(isQ ? Ah : Bh);
  u32* __restrict__ Ol = (u32*)(isQ ? Al : Bl);
#pragma unroll
  for (int p = 0; p < 5; p++) {
    float g = (f[p] - bc[p]) * hrcp(bc[5 + p]);
    float gp = __shfl_xor(g, 1);
    if (!(t & 1)) {
      u16 h0 = f2bf(g), h1 = f2bf(gp);
      float l0 = g - bf2f(h0);
      float l1 = gp - bf2f(h1);
      const size_t o = ((size_t)n * 5 + p) * 320 + (t >> 1);
      Oh[o] = (u32)h0 | ((u32)h1 << 16);
      Ol[o] = (u32)f2bf(l0) | ((u32)f2bf(l1) << 16);
    }
  }
}

// ---------------------------------------------------------------------------
// sim GEMM: C[10240][320] = A[10240][640] * Bt[320][640]^T, split-bf16 3-pass.
// Tile 128x64, BK=32, 4 waves (2x2), dbuf LDS, XOR-swizzled both sides,
// counted vmcnt(6). Epilogue -> packed f32. (Verified R5-R9.)
// ---------------------------------------------------------------------------
__global__ __launch_bounds__(256) void gemm_sim_kernel(const u16* __restrict__ Ah,
                                                       const u16* __restrict__ Al,
                                                       const u16* __restrict__ Bh,
                                                       const u16* __restrict__ Bl,
                                                       float* __restrict__ packed)
{
  __shared__ u16 ldsAh[2][128 * 32];
  __shared__ u16 ldsAl[2][128 * 32];
  __shared__ u16 ldsBh[2][64 * 32];
  __shared__ u16 ldsBl[2][64 * 32];
  const int bid = blockIdx.x;
  const int wg = (bid & 7) * 50 + (bid >> 3);  // bijective, 400 = 8*50
  const int bm = wg / 5;
  const int bn = wg % 5;
  const int row0 = bm * 128;
  const int col0 = bn * 64;
  const int tid = threadIdx.x;
  const int lane = tid & 63;
  const int w = tid >> 6;
  const int wr = w >> 1;
  const int wc = w & 1;

  f32x4 acc[4][2];
#pragma unroll
  for (int m = 0; m < 4; m++)
#pragma unroll
    for (int n = 0; n < 2; n++) acc[m][n] = (f32x4){0.f, 0.f, 0.f, 0.f};

  auto stage = [&](int kt, int b) {
    const int k0 = kt * 32;
#pragma unroll
    for (int i = 0; i < 2; i++) {
      const int s = tid + i * 256;
      const int r = s >> 2;
      const int chl = (s & 3) ^ ((r >> 1) & 3);
      const size_t go = (size_t)(row0 + r) * 640 + k0 + chl * 8;
      __builtin_amdgcn_global_load_lds((glb_ptr_t)(Ah + go),
                                       (lds_ptr_t)(&ldsAh[b][s * 8]), 16, 0, 0);
      __builtin_amdgcn_global_load_lds((glb_ptr_t)(Al + go),
                                       (lds_ptr_t)(&ldsAl[b][s * 8]), 16, 0, 0);
    }
    {
      const int r = tid >> 2;
      const int chl = (tid & 3) ^ ((r >> 1) & 3);
      const size_t go = (size_t)(col0 + r) * 640 + k0 + chl * 8;
      __builtin_amdgcn_global_load_lds((glb_ptr_t)(Bh + go),
                                       (lds_ptr_t)(&ldsBh[b][tid * 8]), 16, 0, 0);
      __builtin_amdgcn_global_load_lds((glb_ptr_t)(Bl + go),
                                       (lds_ptr_t)(&ldsBl[b][tid * 8]), 16, 0, 0);
    }
  };

  stage(0, 0);
  for (int kt = 0; kt < 20; ++kt) {
    const int b = kt & 1;
    if (kt < 19) {
      stage(kt + 1, b ^ 1);
      asm volatile("s_waitcnt vmcnt(6)" ::: "memory");
    } else {
      asm volatile("s_waitcnt vmcnt(0)" ::: "memory");
    }
    __builtin_amdgcn_sched_barrier(0);
    __builtin_amdgcn_s_barrier();

    const int rq = lane & 15;
    const int kq = lane >> 4;
    short8 ah[4], al[4], bh[2], bl[2];
#pragma unroll
    for (int m = 0; m < 4; m++) {
      const int row = wr * 64 + m * 16 + rq;
      const int off = row * 32 + ((kq ^ ((row >> 1) & 3)) * 8);
      ah[m] = *(const short8*)&ldsAh[b][off];
      al[m] = *(const short8*)&ldsAl[b][off];
    }
#pragma unroll
    for (int n = 0; n < 2; n++) {
      const int row = wc * 32 + n * 16 + rq;
      const int off = row * 32 + ((kq ^ ((row >> 1) & 3)) * 8);
      bh[n] = *(const short8*)&ldsBh[b][off];
      bl[n] = *(const short8*)&ldsBl[b][off];
    }
#pragma unroll
    for (int m = 0; m < 4; m++)
#pragma unroll
      for (int n = 0; n < 2; n++) {
        acc[m][n] = __builtin_amdgcn_mfma_f32_16x16x32_bf16(ah[m], bh[n], acc[m][n], 0, 0, 0);
        acc[m][n] = __builtin_amdgcn_mfma_f32_16x16x32_bf16(ah[m], bl[n], acc[m][n], 0, 0, 0);
        acc[m][n] = __builtin_amdgcn_mfma_f32_16x16x32_bf16(al[m], bh[n], acc[m][n], 0, 0, 0);
      }

    __builtin_amdgcn_sched_barrier(0);
    __builtin_amdgcn_s_barrier();
  }

#pragma unroll
  for (int m = 0; m < 4; m++)
#pragma unroll
    for (int n = 0; n < 2; n++)
#pragma unroll
      for (int r = 0; r < 4; r++) {
        const unsigned R = row0 + wr * 64 + m * 16 + (lane >> 4) * 4 + r;
        const unsigned Cc = col0 + wc * 32 + n * 16 + (lane & 15);
        const unsigned mq = R / 5u;
        const unsigned i = R - mq * 5u;
        const unsigned wp = Cc / 5u;
        const unsigned j = Cc - wp * 5u;
        packed[((size_t)mq * 64 + wp) * 32 + i * 5 + j] = acc[m][n][r];
      }
}

// ---------------------------------------------------------------------------
// Sinkhorn: thread <-> (m,w). dot reconstructed from sim diagonal + stats.
// ---------------------------------------------------------------------------
__global__ __launch_bounds__(256) void sink3_kernel(const float* __restrict__ packed,
                                                    const float* __restrict__ statsQ,
                                                    const float* __restrict__ statsP,
                                                    float* __restrict__ out)
{
  const int tid = threadIdx.x;
  const int lane = tid & 63;
  const int wv = tid >> 6;
  const int m = blockIdx.x * 4 + wv;
  const float* pb = packed + ((size_t)m * 64 + lane) * 32;

  float sm[25];
  {
    const f32x4* pv = (const f32x4*)pb;
#pragma unroll
    for (int q = 0; q < 6; q++) {
      f32x4 t = pv[q];
#pragma unroll
      for (int e = 0; e < 4; e++) sm[q * 4 + e] = t[e];
    }
    sm[24] = pb[24];
  }

  float dot[5];
#pragma unroll
  for (int p = 0; p < 5; p++) {
    float muq = statsQ[(size_t)m * 10 + p];
    float nq = statsQ[(size_t)m * 10 + 5 + p];
    float mup = statsP[p * NW + lane];
    float np = statsP[(5 + p) * NW + lane];
    dot[p] = sm[p * 5 + p] * (nq * np) + 640.0f * muq * mup;
  }

  out[(size_t)m * 64 + lane] = sinkhorn_core(sm, dot);
}

extern "C" void kernel_launch(void* const* d_in, const int* in_sizes, int n_in,
                              void* d_out, int out_size, void* d_ws, size_t ws_size,
                              hipStream_t stream) {
  const float* proto = (const float*)d_in[0];  // (1,64,640,5,5)
  const float* query = (const float*)d_in[1];  // (2048,640,5,5)
  float* out = (float*)d_out;                  // (2048,64) f32

  const size_t nA = (size_t)NQ * 5 * NC;   // 6,553,600 u16
  const size_t nB = (size_t)NW * 5 * NC;   // 204,800 u16
  u16* Ah = (u16*)d_ws;
  u16* Al = Ah + nA;
  u16* Bh = Al + nA;
  u16* Bl = Bh + nB;
  float* statsQ = (float*)(Bl + nB);
  float* statsP = statsQ + (size_t)NQ * 10;
  float* packed = statsP + 10 * NW;

  feat_kernel<<<NQ + NW, 640, 0, stream>>>(query, proto, Ah, Al, Bh, Bl, statsQ, statsP);
  gemm_sim_kernel<<<400, 256, 0, stream>>>(Ah, Al, Bh, Bl, packed);
  sink3_kernel<<<NQ / 4, 256, 0, stream>>>(packed, statsQ, statsP, out);
}

// Round 11
// 89.421 us; speedup vs baseline: 1.1859x; 1.1859x over previous
//
#include <hip/hip_runtime.h>

#define NC 640
#define NQ 2048
#define NW 64

typedef unsigned short u16;
typedef unsigned int u32;
typedef __attribute__((ext_vector_type(8))) short short8;
typedef __attribute__((ext_vector_type(4))) float f32x4;
typedef __attribute__((ext_vector_type(2))) float f32x2;
typedef __attribute__((address_space(3))) void* lds_ptr_t;
typedef const __attribute__((address_space(1))) void* glb_ptr_t;

// KC = log2(e)/EPS, EPS = 0.05
constexpr float KC = 28.853900817779268f;

static __device__ __forceinline__ float hrcp(float x) { return __builtin_amdgcn_rcpf(x); }
static __device__ __forceinline__ u16 f2bf(float f) {
  u32 u = __float_as_uint(f);
  u += 0x7FFF + ((u >> 16) & 1);
  return (u16)(u >> 16);
}
static __device__ __forceinline__ float bf2f(u16 h) {
  return __uint_as_float(((u32)h) << 16);
}

// ---------------------------------------------------------------------------
// Sinkhorn core with f32x2-packed FMA chains (v_pk_fma_f32).
// ---------------------------------------------------------------------------
static __device__ __forceinline__ float sinkhorn_core(const float* sm, const float* dot) {
  float a[5];
  float suma = 0.f;
#pragma unroll
  for (int p = 0; p < 5; p++) {
    a[p] = fmaxf(dot[p], 0.f) + 0.00101f;
    suma += a[p];
  }
  float rs = 5.0f / suma;
#pragma unroll
  for (int p = 0; p < 5; p++) a[p] *= rs;

  float Km[25];
#pragma unroll
  for (int i = 0; i < 25; i++) Km[i] = __builtin_amdgcn_exp2f((sm[i] - 1.0f) * KC);

  f32x2 KP01[5], KP23[5], KQ01[5], KQ23[5];
#pragma unroll
  for (int j = 0; j < 5; j++) {
    KP01[j] = (f32x2){Km[0 * 5 + j], Km[1 * 5 + j]};
    KP23[j] = (f32x2){Km[2 * 5 + j], Km[3 * 5 + j]};
  }
#pragma unroll
  for (int i = 0; i < 5; i++) {
    KQ01[i] = (f32x2){Km[i * 5 + 0], Km[i * 5 + 1]};
    KQ23[i] = (f32x2){Km[i * 5 + 2], Km[i * 5 + 3]};
  }

  float u[5], v[5];
#pragma unroll
  for (int p = 0; p < 5; p++) { u[p] = 1.f; v[p] = 1.f; }

  for (int it = 0; it < 100; ++it) {
    f32x2 kv01 = (f32x2){0.f, 0.f}, kv23 = (f32x2){0.f, 0.f};
    float kv4 = 0.f;
#pragma unroll
    for (int j = 0; j < 5; j++) {
      f32x2 vb = (f32x2){v[j], v[j]};
      kv01 = __builtin_elementwise_fma(KP01[j], vb, kv01);
      kv23 = __builtin_elementwise_fma(KP23[j], vb, kv23);
      kv4 = fmaf(Km[20 + j], v[j], kv4);
    }
    u[0] = a[0] * hrcp(kv01.x);
    u[1] = a[1] * hrcp(kv01.y);
    u[2] = a[2] * hrcp(kv23.x);
    u[3] = a[3] * hrcp(kv23.y);
    u[4] = a[4] * hrcp(kv4);
    f32x2 ku01 = (f32x2){0.f, 0.f}, ku23 = (f32x2){0.f, 0.f};
    float ku4 = 0.f;
#pragma unroll
    for (int i = 0; i < 5; i++) {
      f32x2 ub = (f32x2){u[i], u[i]};
      ku01 = __builtin_elementwise_fma(KQ01[i], ub, ku01);
      ku23 = __builtin_elementwise_fma(KQ23[i], ub, ku23);
      ku4 = fmaf(Km[i * 5 + 4], u[i], ku4);
    }
    v[0] = a[0] * hrcp(ku01.x);
    v[1] = a[1] * hrcp(ku01.y);
    v[2] = a[2] * hrcp(ku23.x);
    v[3] = a[3] * hrcp(ku23.y);
    v[4] = a[4] * hrcp(ku4);
  }

  float acc = 0.f;
#pragma unroll
  for (int i = 0; i < 5; i++)
#pragma unroll
    for (int j = 0; j < 5; j++)
      acc += u[i] * Km[i * 5 + j] * v[j] * sm[i * 5 + j];
  return acc * 2.5f;
}

// ---------------------------------------------------------------------------
// Feature kernel v7 (R1 direct-read structure + later wins): block = sample,
// 320 threads (5 waves); thread owns channels {t, t+320}; 25 scalar dword
// loads per channel straight from global (wave spans 6.4KB -> L1-reused; no
// input LDS, no load barrier). LDS = 60B reduce scratch -> occupancy 6
// blocks/CU (30 waves). Two tiny syncthreads for block stats. Outputs via
// shfl-pair-packed u32 hi/lo stores. Blocks [0,2048): query; rest: proto.
// ---------------------------------------------------------------------------
__global__ __launch_bounds__(320) void feat_kernel(const float* __restrict__ q,
                                                   const float* __restrict__ pr,
                                                   u16* __restrict__ Ah,
                                                   u16* __restrict__ Al,
                                                   u16* __restrict__ Bh,
                                                   u16* __restrict__ Bl,
                                                   float* __restrict__ statsQ,
                                                   float* __restrict__ statsP)
{
  __shared__ float wred[5][10];
  __shared__ float bc[10];
  const int bid = blockIdx.x;
  const bool isQ = (bid < NQ);
  const int n = isQ ? bid : bid - NQ;
  const float* __restrict__ x = (isQ ? q : pr) + (size_t)n * 16000;
  const int t = threadIdx.x;
  const int lane = t & 63;
  const int wv = t >> 6;   // 0..4

  float f[2][5];
  float s1[5] = {0.f, 0.f, 0.f, 0.f, 0.f};
  float s2[5] = {0.f, 0.f, 0.f, 0.f, 0.f};

#pragma unroll
  for (int h = 0; h < 2; h++) {
    const float* v = x + (size_t)(t + h * 320) * 25;
    float w[25];
#pragma unroll
    for (int i = 0; i < 25; i++) w[i] = v[i];
    float lt = 0.f, rt = 0.f, mid = 0.f, lb = 0.f, rb = 0.f;
#pragma unroll
    for (int a = 0; a < 3; a++)
#pragma unroll
      for (int c = 0; c < 3; c++) {
        lt += w[a * 5 + c];
        rt += w[(a + 2) * 5 + c];
        lb += w[a * 5 + (c + 2)];
        rb += w[(a + 2) * 5 + (c + 2)];
      }
#pragma unroll
    for (int a = 1; a < 5; a++)
#pragma unroll
      for (int c = 1; c < 5; c++) mid += w[a * 5 + c];
    f[h][0] = lt * (1.f / 9.f);
    f[h][1] = rt * (1.f / 9.f);
    f[h][2] = mid * (1.f / 16.f);
    f[h][3] = lb * (1.f / 9.f);
    f[h][4] = rb * (1.f / 9.f);
#pragma unroll
    for (int p = 0; p < 5; p++) {
      s1[p] += f[h][p];
      s2[p] = fmaf(f[h][p], f[h][p], s2[p]);
    }
  }

  // wave reduce (64 lanes), then cross-wave via 60B LDS
  {
    float s[10];
#pragma unroll
    for (int p = 0; p < 5; p++) { s[p] = s1[p]; s[5 + p] = s2[p]; }
#pragma unroll
    for (int off = 32; off > 0; off >>= 1)
#pragma unroll
      for (int k = 0; k < 10; k++) s[k] += __shfl_xor(s[k], off);
    if (lane == 0) {
#pragma unroll
      for (int k = 0; k < 10; k++) wred[wv][k] = s[k];
    }
  }
  __syncthreads();
  if (t < 5) {
    float a1 = 0.f, a2 = 0.f;
#pragma unroll
    for (int w = 0; w < 5; w++) { a1 += wred[w][t]; a2 += wred[w][5 + t]; }
    float mu = a1 * (1.0f / NC);
    float n2 = fmaxf(a2 - (float)NC * mu * mu, 0.0f);
    float nrm = fmaxf(sqrtf(n2), 1e-8f);
    bc[t] = mu;
    bc[5 + t] = nrm;
  }
  __syncthreads();

  if (t < 5) {
    if (isQ) {
      statsQ[(size_t)n * 10 + t] = bc[t];
      statsQ[(size_t)n * 10 + 5 + t] = bc[5 + t];
    } else {
      statsP[t * NW + n] = bc[t];
      statsP[(5 + t) * NW + n] = bc[5 + t];
    }
  }

  // centered-normalized split-bf16 writes: shfl pair-pack, even lanes store
  u32* __restrict__ Oh = (u32*)(isQ ? Ah : Bh);
  u32* __restrict__ Ol = (u32*)(isQ ? Al : Bl);
#pragma unroll
  for (int h = 0; h < 2; h++)
#pragma unroll
    for (int p = 0; p < 5; p++) {
      float g = (f[h][p] - bc[p]) * hrcp(bc[5 + p]);
      float gp = __shfl_xor(g, 1);
      if (!(t & 1)) {
        u16 h0 = f2bf(g), h1 = f2bf(gp);
        float l0 = g - bf2f(h0);
        float l1 = gp - bf2f(h1);
        const size_t o = ((size_t)n * 5 + p) * 320 + (t >> 1) + h * 160;
        Oh[o] = (u32)h0 | ((u32)h1 << 16);
        Ol[o] = (u32)f2bf(l0) | ((u32)f2bf(l1) << 16);
      }
    }
}

// ---------------------------------------------------------------------------
// sim GEMM: C[10240][320] = A[10240][640] * Bt[320][640]^T, split-bf16 3-pass.
// Tile 128x64, BK=32, 4 waves (2x2), dbuf LDS, XOR-swizzled both sides,
// counted vmcnt(6). Epilogue -> packed f32. (Verified R5-R10.)
// ---------------------------------------------------------------------------
__global__ __launch_bounds__(256) void gemm_sim_kernel(const u16* __restrict__ Ah,
                                                       const u16* __restrict__ Al,
                                                       const u16* __restrict__ Bh,
                                                       const u16* __restrict__ Bl,
                                                       float* __restrict__ packed)
{
  __shared__ u16 ldsAh[2][128 * 32];
  __shared__ u16 ldsAl[2][128 * 32];
  __shared__ u16 ldsBh[2][64 * 32];
  __shared__ u16 ldsBl[2][64 * 32];
  const int bid = blockIdx.x;
  const int wg = (bid & 7) * 50 + (bid >> 3);  // bijective, 400 = 8*50
  const int bm = wg / 5;
  const int bn = wg % 5;
  const int row0 = bm * 128;
  const int col0 = bn * 64;
  const int tid = threadIdx.x;
  const int lane = tid & 63;
  const int w = tid >> 6;
  const int wr = w >> 1;
  const int wc = w & 1;

  f32x4 acc[4][2];
#pragma unroll
  for (int m = 0; m < 4; m++)
#pragma unroll
    for (int n = 0; n < 2; n++) acc[m][n] = (f32x4){0.f, 0.f, 0.f, 0.f};

  auto stage = [&](int kt, int b) {
    const int k0 = kt * 32;
#pragma unroll
    for (int i = 0; i < 2; i++) {
      const int s = tid + i * 256;
      const int r = s >> 2;
      const int chl = (s & 3) ^ ((r >> 1) & 3);
      const size_t go = (size_t)(row0 + r) * 640 + k0 + chl * 8;
      __builtin_amdgcn_global_load_lds((glb_ptr_t)(Ah + go),
                                       (lds_ptr_t)(&ldsAh[b][s * 8]), 16, 0, 0);
      __builtin_amdgcn_global_load_lds((glb_ptr_t)(Al + go),
                                       (lds_ptr_t)(&ldsAl[b][s * 8]), 16, 0, 0);
    }
    {
      const int r = tid >> 2;
      const int chl = (tid & 3) ^ ((r >> 1) & 3);
      const size_t go = (size_t)(col0 + r) * 640 + k0 + chl * 8;
      __builtin_amdgcn_global_load_lds((glb_ptr_t)(Bh + go),
                                       (lds_ptr_t)(&ldsBh[b][tid * 8]), 16, 0, 0);
      __builtin_amdgcn_global_load_lds((glb_ptr_t)(Bl + go),
                                       (lds_ptr_t)(&ldsBl[b][tid * 8]), 16, 0, 0);
    }
  };

  stage(0, 0);
  for (int kt = 0; kt < 20; ++kt) {
    const int b = kt & 1;
    if (kt < 19) {
      stage(kt + 1, b ^ 1);
      asm volatile("s_waitcnt vmcnt(6)" ::: "memory");
    } else {
      asm volatile("s_waitcnt vmcnt(0)" ::: "memory");
    }
    __builtin_amdgcn_sched_barrier(0);
    __builtin_amdgcn_s_barrier();

    const int rq = lane & 15;
    const int kq = lane >> 4;
    short8 ah[4], al[4], bh[2], bl[2];
#pragma unroll
    for (int m = 0; m < 4; m++) {
      const int row = wr * 64 + m * 16 + rq;
      const int off = row * 32 + ((kq ^ ((row >> 1) & 3)) * 8);
      ah[m] = *(const short8*)&ldsAh[b][off];
      al[m] = *(const short8*)&ldsAl[b][off];
    }
#pragma unroll
    for (int n = 0; n < 2; n++) {
      const int row = wc * 32 + n * 16 + rq;
      const int off = row * 32 + ((kq ^ ((row >> 1) & 3)) * 8);
      bh[n] = *(const short8*)&ldsBh[b][off];
      bl[n] = *(const short8*)&ldsBl[b][off];
    }
#pragma unroll
    for (int m = 0; m < 4; m++)
#pragma unroll
      for (int n = 0; n < 2; n++) {
        acc[m][n] = __builtin_amdgcn_mfma_f32_16x16x32_bf16(ah[m], bh[n], acc[m][n], 0, 0, 0);
        acc[m][n] = __builtin_amdgcn_mfma_f32_16x16x32_bf16(ah[m], bl[n], acc[m][n], 0, 0, 0);
        acc[m][n] = __builtin_amdgcn_mfma_f32_16x16x32_bf16(al[m], bh[n], acc[m][n], 0, 0, 0);
      }

    __builtin_amdgcn_sched_barrier(0);
    __builtin_amdgcn_s_barrier();
  }

#pragma unroll
  for (int m = 0; m < 4; m++)
#pragma unroll
    for (int n = 0; n < 2; n++)
#pragma unroll
      for (int r = 0; r < 4; r++) {
        const unsigned R = row0 + wr * 64 + m * 16 + (lane >> 4) * 4 + r;
        const unsigned Cc = col0 + wc * 32 + n * 16 + (lane & 15);
        const unsigned mq = R / 5u;
        const unsigned i = R - mq * 5u;
        const unsigned wp = Cc / 5u;
        const unsigned j = Cc - wp * 5u;
        packed[((size_t)mq * 64 + wp) * 32 + i * 5 + j] = acc[m][n][r];
      }
}

// ---------------------------------------------------------------------------
// Sinkhorn: thread <-> (m,w). dot reconstructed from sim diagonal + stats.
// ---------------------------------------------------------------------------
__global__ __launch_bounds__(256) void sink3_kernel(const float* __restrict__ packed,
                                                    const float* __restrict__ statsQ,
                                                    const float* __restrict__ statsP,
                                                    float* __restrict__ out)
{
  const int tid = threadIdx.x;
  const int lane = tid & 63;
  const int wv = tid >> 6;
  const int m = blockIdx.x * 4 + wv;
  const float* pb = packed + ((size_t)m * 64 + lane) * 32;

  float sm[25];
  {
    const f32x4* pv = (const f32x4*)pb;
#pragma unroll
    for (int q = 0; q < 6; q++) {
      f32x4 t = pv[q];
#pragma unroll
      for (int e = 0; e < 4; e++) sm[q * 4 + e] = t[e];
    }
    sm[24] = pb[24];
  }

  float dot[5];
#pragma unroll
  for (int p = 0; p < 5; p++) {
    float muq = statsQ[(size_t)m * 10 + p];
    float nq = statsQ[(size_t)m * 10 + 5 + p];
    float mup = statsP[p * NW + lane];
    float np = statsP[(5 + p) * NW + lane];
    dot[p] = sm[p * 5 + p] * (nq * np) + 640.0f * muq * mup;
  }

  out[(size_t)m * 64 + lane] = sinkhorn_core(sm, dot);
}

extern "C" void kernel_launch(void* const* d_in, const int* in_sizes, int n_in,
                              void* d_out, int out_size, void* d_ws, size_t ws_size,
                              hipStream_t stream) {
  const float* proto = (const float*)d_in[0];  // (1,64,640,5,5)
  const float* query = (const float*)d_in[1];  // (2048,640,5,5)
  float* out = (float*)d_out;                  // (2048,64) f32

  const size_t nA = (size_t)NQ * 5 * NC;   // 6,553,600 u16
  const size_t nB = (size_t)NW * 5 * NC;   // 204,800 u16
  u16* Ah = (u16*)d_ws;
  u16* Al = Ah + nA;
  u16* Bh = Al + nA;
  u16* Bl = Bh + nB;
  float* statsQ = (float*)(Bl + nB);
  float* statsP = statsQ + (size_t)NQ * 10;
  float* packed = statsP + 10 * NW;

  feat_kernel<<<NQ + NW, 320, 0, stream>>>(query, proto, Ah, Al, Bh, Bl, statsQ, statsP);
  gemm_sim_kernel<<<400, 256, 0, stream>>>(Ah, Al, Bh, Bl, packed);
  sink3_kernel<<<NQ / 4, 256, 0, stream>>>(packed, statsQ, statsP, out);
}

// Round 12
// 84.230 us; speedup vs baseline: 1.2590x; 1.0616x over previous
//
#include <hip/hip_runtime.h>

#define NC 640
#define NQ 2048
#define NW 64

typedef unsigned short u16;
typedef unsigned int u32;
typedef __attribute__((ext_vector_type(8))) short short8;
typedef __attribute__((ext_vector_type(4))) float f32x4;
typedef __attribute__((ext_vector_type(2))) float f32x2;
typedef __attribute__((address_space(3))) void* lds_ptr_t;
typedef const __attribute__((address_space(1))) void* glb_ptr_t;

// KC = log2(e)/EPS, EPS = 0.05
constexpr float KC = 28.853900817779268f;

static __device__ __forceinline__ float hrcp(float x) { return __builtin_amdgcn_rcpf(x); }
static __device__ __forceinline__ u16 f2bf(float f) {
  u32 u = __float_as_uint(f);
  u += 0x7FFF + ((u >> 16) & 1);
  return (u16)(u >> 16);
}
static __device__ __forceinline__ float bf2f(u16 h) {
  return __uint_as_float(((u32)h) << 16);
}

// ---------------------------------------------------------------------------
// Sinkhorn core with f32x2-packed FMA chains (v_pk_fma_f32).
// ---------------------------------------------------------------------------
static __device__ __forceinline__ float sinkhorn_core(const float* sm, const float* dot) {
  float a[5];
  float suma = 0.f;
#pragma unroll
  for (int p = 0; p < 5; p++) {
    a[p] = fmaxf(dot[p], 0.f) + 0.00101f;
    suma += a[p];
  }
  float rs = 5.0f / suma;
#pragma unroll
  for (int p = 0; p < 5; p++) a[p] *= rs;

  float Km[25];
#pragma unroll
  for (int i = 0; i < 25; i++) Km[i] = __builtin_amdgcn_exp2f((sm[i] - 1.0f) * KC);

  f32x2 KP01[5], KP23[5], KQ01[5], KQ23[5];
#pragma unroll
  for (int j = 0; j < 5; j++) {
    KP01[j] = (f32x2){Km[0 * 5 + j], Km[1 * 5 + j]};
    KP23[j] = (f32x2){Km[2 * 5 + j], Km[3 * 5 + j]};
  }
#pragma unroll
  for (int i = 0; i < 5; i++) {
    KQ01[i] = (f32x2){Km[i * 5 + 0], Km[i * 5 + 1]};
    KQ23[i] = (f32x2){Km[i * 5 + 2], Km[i * 5 + 3]};
  }

  float u[5], v[5];
#pragma unroll
  for (int p = 0; p < 5; p++) { u[p] = 1.f; v[p] = 1.f; }

  for (int it = 0; it < 100; ++it) {
    f32x2 kv01 = (f32x2){0.f, 0.f}, kv23 = (f32x2){0.f, 0.f};
    float kv4 = 0.f;
#pragma unroll
    for (int j = 0; j < 5; j++) {
      f32x2 vb = (f32x2){v[j], v[j]};
      kv01 = __builtin_elementwise_fma(KP01[j], vb, kv01);
      kv23 = __builtin_elementwise_fma(KP23[j], vb, kv23);
      kv4 = fmaf(Km[20 + j], v[j], kv4);
    }
    u[0] = a[0] * hrcp(kv01.x);
    u[1] = a[1] * hrcp(kv01.y);
    u[2] = a[2] * hrcp(kv23.x);
    u[3] = a[3] * hrcp(kv23.y);
    u[4] = a[4] * hrcp(kv4);
    f32x2 ku01 = (f32x2){0.f, 0.f}, ku23 = (f32x2){0.f, 0.f};
    float ku4 = 0.f;
#pragma unroll
    for (int i = 0; i < 5; i++) {
      f32x2 ub = (f32x2){u[i], u[i]};
      ku01 = __builtin_elementwise_fma(KQ01[i], ub, ku01);
      ku23 = __builtin_elementwise_fma(KQ23[i], ub, ku23);
      ku4 = fmaf(Km[i * 5 + 4], u[i], ku4);
    }
    v[0] = a[0] * hrcp(ku01.x);
    v[1] = a[1] * hrcp(ku01.y);
    v[2] = a[2] * hrcp(ku23.x);
    v[3] = a[3] * hrcp(ku23.y);
    v[4] = a[4] * hrcp(ku4);
  }

  float acc = 0.f;
#pragma unroll
  for (int i = 0; i < 5; i++)
#pragma unroll
    for (int j = 0; j < 5; j++)
      acc += u[i] * Km[i * 5 + j] * v[j] * sm[i * 5 + j];
  return acc * 2.5f;
}

// ---------------------------------------------------------------------------
// Feature kernel v3 (best measured, R7 = 84.8us total): wave = half-sample
// (320 channels, 5 chunks of 64). Chunk = linear 6.4KB DMA (global_load_lds,
// 6x16B + 1x4B per lane, coalesced), per-wave double-buffered, vmcnt(7).
// Lane reads its own channel (l*25+j: conflict-free). One __syncthreads for
// the 2-wave pair reduce. Block = 2 samples (4 waves).
// Blocks [0,1024): query; [1024,1056): proto.
// ---------------------------------------------------------------------------
__global__ __launch_bounds__(256) void feat_kernel(const float* __restrict__ q,
                                                   const float* __restrict__ pr,
                                                   u16* __restrict__ Ah,
                                                   u16* __restrict__ Al,
                                                   u16* __restrict__ Bh,
                                                   u16* __restrict__ Bl,
                                                   float* __restrict__ statsQ,
                                                   float* __restrict__ statsP)
{
  __shared__ float ldsW[4][2][1600];   // 51.2 KB: per-wave double buffer
  __shared__ float sred[4][10];
  const int lane = threadIdx.x & 63;
  const int wv = threadIdx.x >> 6;
  const int sid = blockIdx.x * 2 + (wv >> 1);   // sample id 0..2111
  const int h = wv & 1;                          // half: channels [320h, 320h+320)
  const bool isQ = (sid < NQ);
  const int n = isQ ? sid : sid - NQ;
  const float* __restrict__ x = (isQ ? q : pr) + (size_t)n * 16000;

  // stage chunk k (64 channels = 1600 floats) into buffer b, linear copy
  auto stage = [&](int k, int b) {
    asm volatile("s_waitcnt lgkmcnt(0)" ::: "memory");  // prior reads of b done
    const float* src = x + (size_t)(h * 320 + k * 64) * 25;
#pragma unroll
    for (int i = 0; i < 6; i++) {
      __builtin_amdgcn_global_load_lds((glb_ptr_t)(src + i * 256 + lane * 4),
                                       (lds_ptr_t)(&ldsW[wv][b][i * 256 + lane * 4]),
                                       16, 0, 0);
    }
    __builtin_amdgcn_global_load_lds((glb_ptr_t)(src + 1536 + lane),
                                     (lds_ptr_t)(&ldsW[wv][b][1536 + lane]),
                                     4, 0, 0);
  };

  float f[5][5];   // [chunk][patch]
  float s1[5] = {0.f, 0.f, 0.f, 0.f, 0.f};
  float s2[5] = {0.f, 0.f, 0.f, 0.f, 0.f};

  stage(0, 0);
  for (int k = 0; k < 5; ++k) {
    const int b = k & 1;
    if (k < 4) {
      stage(k + 1, b ^ 1);
      asm volatile("s_waitcnt vmcnt(7)" ::: "memory");
    } else {
      asm volatile("s_waitcnt vmcnt(0)" ::: "memory");
    }
    __builtin_amdgcn_sched_barrier(0);

    float w[25];
#pragma unroll
    for (int j = 0; j < 25; j++) w[j] = ldsW[wv][b][lane * 25 + j];

    float lt = 0.f, rt = 0.f, mid = 0.f, lb = 0.f, rb = 0.f;
#pragma unroll
    for (int a = 0; a < 3; a++)
#pragma unroll
      for (int c = 0; c < 3; c++) {
        lt += w[a * 5 + c];
        rt += w[(a + 2) * 5 + c];
        lb += w[a * 5 + (c + 2)];
        rb += w[(a + 2) * 5 + (c + 2)];
      }
#pragma unroll
    for (int a = 1; a < 5; a++)
#pragma unroll
      for (int c = 1; c < 5; c++) mid += w[a * 5 + c];
    f[k][0] = lt * (1.f / 9.f);
    f[k][1] = rt * (1.f / 9.f);
    f[k][2] = mid * (1.f / 16.f);
    f[k][3] = lb * (1.f / 9.f);
    f[k][4] = rb * (1.f / 9.f);
#pragma unroll
    for (int p = 0; p < 5; p++) {
      s1[p] += f[k][p];
      s2[p] = fmaf(f[k][p], f[k][p], s2[p]);
    }
    __builtin_amdgcn_sched_barrier(0);
  }

  // wave reduce (64 lanes)
#pragma unroll
  for (int off = 32; off > 0; off >>= 1)
#pragma unroll
    for (int p = 0; p < 5; p++) {
      s1[p] += __shfl_xor(s1[p], off);
      s2[p] += __shfl_xor(s2[p], off);
    }

  // pair reduce across the sample's two waves
  if (lane == 0) {
#pragma unroll
    for (int p = 0; p < 5; p++) { sred[wv][p] = s1[p]; sred[wv][5 + p] = s2[p]; }
  }
  __syncthreads();
  const int pw = wv ^ 1;
  float mu[5], rn[5], nrm[5];
#pragma unroll
  for (int p = 0; p < 5; p++) {
    float t1 = s1[p] + sred[pw][p];
    float t2 = s2[p] + sred[pw][5 + p];
    mu[p] = t1 * (1.0f / NC);
    float n2 = fmaxf(t2 - (float)NC * mu[p] * mu[p], 0.0f);
    nrm[p] = fmaxf(sqrtf(n2), 1e-8f);
    rn[p] = 1.0f / nrm[p];
  }

  if (lane == 0 && h == 0) {
    if (isQ) {
#pragma unroll
      for (int p = 0; p < 5; p++) {
        statsQ[(size_t)n * 10 + p] = mu[p];
        statsQ[(size_t)n * 10 + 5 + p] = nrm[p];
      }
    } else {
#pragma unroll
      for (int p = 0; p < 5; p++) {
        statsP[p * NW + n] = mu[p];
        statsP[(5 + p) * NW + n] = nrm[p];
      }
    }
  }

  // centered-normalized split-bf16 writes (coalesced: lane -> channel)
  u16* __restrict__ Oh = isQ ? Ah : Bh;
  u16* __restrict__ Ol = isQ ? Al : Bl;
#pragma unroll
  for (int p = 0; p < 5; p++) {
    const size_t rowb = ((size_t)n * 5 + p) * 640;
#pragma unroll
    for (int k = 0; k < 5; k++) {
      const int c = h * 320 + k * 64 + lane;
      float g = (f[k][p] - mu[p]) * rn[p];
      u16 hi = f2bf(g);
      float lo = g - bf2f(hi);
      Oh[rowb + c] = hi;
      Ol[rowb + c] = f2bf(lo);
    }
  }
}

// ---------------------------------------------------------------------------
// sim GEMM: C[10240][320] = A[10240][640] * Bt[320][640]^T, split-bf16 3-pass.
// Tile 128x64, BK=32, 4 waves (2x2), dbuf LDS, XOR-swizzled both sides,
// counted vmcnt(6). Epilogue -> packed f32. (Verified R5-R11.)
// ---------------------------------------------------------------------------
__global__ __launch_bounds__(256) void gemm_sim_kernel(const u16* __restrict__ Ah,
                                                       const u16* __restrict__ Al,
                                                       const u16* __restrict__ Bh,
                                                       const u16* __restrict__ Bl,
                                                       float* __restrict__ packed)
{
  __shared__ u16 ldsAh[2][128 * 32];
  __shared__ u16 ldsAl[2][128 * 32];
  __shared__ u16 ldsBh[2][64 * 32];
  __shared__ u16 ldsBl[2][64 * 32];
  const int bid = blockIdx.x;
  const int wg = (bid & 7) * 50 + (bid >> 3);  // bijective, 400 = 8*50
  const int bm = wg / 5;
  const int bn = wg % 5;
  const int row0 = bm * 128;
  const int col0 = bn * 64;
  const int tid = threadIdx.x;
  const int lane = tid & 63;
  const int w = tid >> 6;
  const int wr = w >> 1;
  const int wc = w & 1;

  f32x4 acc[4][2];
#pragma unroll
  for (int m = 0; m < 4; m++)
#pragma unroll
    for (int n = 0; n < 2; n++) acc[m][n] = (f32x4){0.f, 0.f, 0.f, 0.f};

  auto stage = [&](int kt, int b) {
    const int k0 = kt * 32;
#pragma unroll
    for (int i = 0; i < 2; i++) {
      const int s = tid + i * 256;
      const int r = s >> 2;
      const int chl = (s & 3) ^ ((r >> 1) & 3);
      const size_t go = (size_t)(row0 + r) * 640 + k0 + chl * 8;
      __builtin_amdgcn_global_load_lds((glb_ptr_t)(Ah + go),
                                       (lds_ptr_t)(&ldsAh[b][s * 8]), 16, 0, 0);
      __builtin_amdgcn_global_load_lds((glb_ptr_t)(Al + go),
                                       (lds_ptr_t)(&ldsAl[b][s * 8]), 16, 0, 0);
    }
    {
      const int r = tid >> 2;
      const int chl = (tid & 3) ^ ((r >> 1) & 3);
      const size_t go = (size_t)(col0 + r) * 640 + k0 + chl * 8;
      __builtin_amdgcn_global_load_lds((glb_ptr_t)(Bh + go),
                                       (lds_ptr_t)(&ldsBh[b][tid * 8]), 16, 0, 0);
      __builtin_amdgcn_global_load_lds((glb_ptr_t)(Bl + go),
                                       (lds_ptr_t)(&ldsBl[b][tid * 8]), 16, 0, 0);
    }
  };

  stage(0, 0);
  for (int kt = 0; kt < 20; ++kt) {
    const int b = kt & 1;
    if (kt < 19) {
      stage(kt + 1, b ^ 1);
      asm volatile("s_waitcnt vmcnt(6)" ::: "memory");
    } else {
      asm volatile("s_waitcnt vmcnt(0)" ::: "memory");
    }
    __builtin_amdgcn_sched_barrier(0);
    __builtin_amdgcn_s_barrier();

    const int rq = lane & 15;
    const int kq = lane >> 4;
    short8 ah[4], al[4], bh[2], bl[2];
#pragma unroll
    for (int m = 0; m < 4; m++) {
      const int row = wr * 64 + m * 16 + rq;
      const int off = row * 32 + ((kq ^ ((row >> 1) & 3)) * 8);
      ah[m] = *(const short8*)&ldsAh[b][off];
      al[m] = *(const short8*)&ldsAl[b][off];
    }
#pragma unroll
    for (int n = 0; n < 2; n++) {
      const int row = wc * 32 + n * 16 + rq;
      const int off = row * 32 + ((kq ^ ((row >> 1) & 3)) * 8);
      bh[n] = *(const short8*)&ldsBh[b][off];
      bl[n] = *(const short8*)&ldsBl[b][off];
    }
#pragma unroll
    for (int m = 0; m < 4; m++)
#pragma unroll
      for (int n = 0; n < 2; n++) {
        acc[m][n] = __builtin_amdgcn_mfma_f32_16x16x32_bf16(ah[m], bh[n], acc[m][n], 0, 0, 0);
        acc[m][n] = __builtin_amdgcn_mfma_f32_16x16x32_bf16(ah[m], bl[n], acc[m][n], 0, 0, 0);
        acc[m][n] = __builtin_amdgcn_mfma_f32_16x16x32_bf16(al[m], bh[n], acc[m][n], 0, 0, 0);
      }

    __builtin_amdgcn_sched_barrier(0);
    __builtin_amdgcn_s_barrier();
  }

#pragma unroll
  for (int m = 0; m < 4; m++)
#pragma unroll
    for (int n = 0; n < 2; n++)
#pragma unroll
      for (int r = 0; r < 4; r++) {
        const unsigned R = row0 + wr * 64 + m * 16 + (lane >> 4) * 4 + r;
        const unsigned Cc = col0 + wc * 32 + n * 16 + (lane & 15);
        const unsigned mq = R / 5u;
        const unsigned i = R - mq * 5u;
        const unsigned wp = Cc / 5u;
        const unsigned j = Cc - wp * 5u;
        packed[((size_t)mq * 64 + wp) * 32 + i * 5 + j] = acc[m][n][r];
      }
}

// ---------------------------------------------------------------------------
// Sinkhorn: thread <-> (m,w). dot reconstructed from sim diagonal + stats.
// ---------------------------------------------------------------------------
__global__ __launch_bounds__(256) void sink3_kernel(const float* __restrict__ packed,
                                                    const float* __restrict__ statsQ,
                                                    const float* __restrict__ statsP,
                                                    float* __restrict__ out)
{
  const int tid = threadIdx.x;
  const int lane = tid & 63;
  const int wv = tid >> 6;
  const int m = blockIdx.x * 4 + wv;
  const float* pb = packed + ((size_t)m * 64 + lane) * 32;

  float sm[25];
  {
    const f32x4* pv = (const f32x4*)pb;
#pragma unroll
    for (int q = 0; q < 6; q++) {
      f32x4 t = pv[q];
#pragma unroll
      for (int e = 0; e < 4; e++) sm[q * 4 + e] = t[e];
    }
    sm[24] = pb[24];
  }

  float dot[5];
#pragma unroll
  for (int p = 0; p < 5; p++) {
    float muq = statsQ[(size_t)m * 10 + p];
    float nq = statsQ[(size_t)m * 10 + 5 + p];
    float mup = statsP[p * NW + lane];
    float np = statsP[(5 + p) * NW + lane];
    dot[p] = sm[p * 5 + p] * (nq * np) + 640.0f * muq * mup;
  }

  out[(size_t)m * 64 + lane] = sinkhorn_core(sm, dot);
}

extern "C" void kernel_launch(void* const* d_in, const int* in_sizes, int n_in,
                              void* d_out, int out_size, void* d_ws, size_t ws_size,
                              hipStream_t stream) {
  const float* proto = (const float*)d_in[0];  // (1,64,640,5,5)
  const float* query = (const float*)d_in[1];  // (2048,640,5,5)
  float* out = (float*)d_out;                  // (2048,64) f32

  const size_t nA = (size_t)NQ * 5 * NC;   // 6,553,600 u16
  const size_t nB = (size_t)NW * 5 * NC;   // 204,800 u16
  u16* Ah = (u16*)d_ws;
  u16* Al = Ah + nA;
  u16* Bh = Al + nA;
  u16* Bl = Bh + nB;
  float* statsQ = (float*)(Bl + nB);
  float* statsP = statsQ + (size_t)NQ * 10;
  float* packed = statsP + 10 * NW;

  feat_kernel<<<(NQ + NW) / 2, 256, 0, stream>>>(query, proto, Ah, Al, Bh, Bl, statsQ, statsP);
  gemm_sim_kernel<<<400, 256, 0, stream>>>(Ah, Al, Bh, Bl, packed);
  sink3_kernel<<<NQ / 4, 256, 0, stream>>>(packed, statsQ, statsP, out);
}